// Round 12
// baseline (209.283 us; speedup 1.0000x reference)
//
#include <hip/hip_runtime.h>
#include <math.h>

#define NN 1024
#define BATCH 32
#define P 8               // blocks per batch
#define NW 4              // waves per block
#define THREADS 256
#define DD 32             // diagonals per interval (needs SW >= DD-1, SW+DD <= 65)
#define SW 32             // row stride between waves
#define SPAN 160          // (NW-1)*SW + 64
#define NT 64             // ceil(2047/DD)
#define RB 4              // fabric ring slots, in PAIRS (power of 2)
#define WLN 2368          // per-block unified weight LUT length (covers m-range + guards)
#define GW 0.05f
#define K2 144.2695040888963f            // (1/gamma)*log2(e): scaled domain
#define INV_K2 0.0069314718055994531f    // gamma*ln2
#define BIGS 1.4426950408889634e11f      // 1e9 * K2

#define EXP2F(x) __builtin_amdgcn_exp2f(x)
#define LOG2F(x) __builtin_amdgcn_logf(x)   // v_log_f32 = log2

typedef unsigned long long u64;

// lanes 1..63 <- src[lane-1]; lane 0 <- oldv[0] (DPP wave_shr:1, bound_ctrl=false)
__device__ __forceinline__ float dppshr(float oldv, float src) {
    return __int_as_float(__builtin_amdgcn_update_dpp(
        __float_as_int(oldv), __float_as_int(src), 0x138, 0xF, 0xF, false));
}

// single-instruction 3-input min/max (bit-identical to nested fmin/fmax for
// finite inputs; all operands here are finite by construction)
__device__ __forceinline__ float min3f(float a, float b, float c) {
    float r;
    asm("v_min3_f32 %0, %1, %2, %3" : "=v"(r) : "v"(a), "v"(b), "v"(c));
    return r;
}
__device__ __forceinline__ float max3f(float a, float b, float c) {
    float r;
    asm("v_max3_f32 %0, %1, %2, %3" : "=v"(r) : "v"(a), "v"(b), "v"(c));
    return r;
}

// self-validating packet: {f32 value | u32 tag} in one atomic u64
__device__ __forceinline__ u64 pk(float v, unsigned tag) {
    return ((u64)tag << 32) | (u64)__float_as_uint(v);
}

// zero acks[256] + all packet words (tags must not alias across runs)
// gx = 256 interfaces * RB * DD * 4 = 131072 u64 -> 512 blocks of 256
__global__ __launch_bounds__(256) void ws_init(int* __restrict__ acks,
                                               u64* __restrict__ gx) {
    if (blockIdx.x == 512) acks[threadIdx.x] = 0;
    else gx[(size_t)blockIdx.x * 256 + threadIdx.x] = 0;
}

// One DP step. DOMASK is compile-time 0/1; entry mask doubles as the i<0
// boundary (R(-1,j)=inf), so the wave containing rows i<0 keeps it forever.
#define STEPBODY(d, DOMASK) do {                                              \
        xv = dppshr(((d) == 0) ? xf0 : xv, xv);     /* x[k-i] flows diag */   \
        const float up = dppshr(((d) == 0) ? bndUp : r1, r1); /* R(i-1,k-1)*/ \
        const float dg = dgp;                                                 \
        const float left = r1;                                                \
        const float diff = ti - xv;                                           \
        const float dk = diff * diff * wreg[(d)];   /* K2-scaled cost */      \
        const float mn = min3f(dg, up, left);                                 \
        const float md = __builtin_amdgcn_fmed3f(dg, up, left);               \
        const float mx = max3f(dg, up, left);                                 \
        const float ss = 1.0f + EXP2F(mn - md) + EXP2F(mn - mx);              \
        float r = dk + mn - LOG2F(ss);                                        \
        if (DOMASK) r = (jj0 >= -(d)) ? r : BIGS;   /* entry-side mask */     \
        r2 = r1; r1 = r; dgp = up;                                            \
    } while (0)

// Overlapped-band wavefront soft-DTW, 8 CUs per batch.
// Round-16: per-step stall attack on the R9/R11 (155.7us) skeleton.
// Accounting closure: 2048 steps x 184 cy = the entire measured runtime --
// there is no residual interval overhead. 184 = ~85 cy issue + ~99 cy
// dependent stall. VGPR_Count=52 proves wreg[32] is NOT resident: the
// compiler re-reads weights from LDS inside the unrolled chain (exposed
// lgkmcnt waits). Fixes: (1) asm "+v" keep-alive pins force wreg (and x
// seeds) into VGPRs at the interval bottom -- ds_reads complete under the
// publish/barrier section, in-loop uses become pure VGPR reads; (2)
// v_min3/v_max3 single-instruction 3-input min/max (-2 issue ops, -1 chain
// op per step; bit-identical for finite values). Protocol byte-identical.
__global__ __launch_bounds__(THREADS, 1) void sdtw_pipe8(
        const float* __restrict__ inp, const float* __restrict__ tgt,
        float* __restrict__ partial, int* __restrict__ acks,
        u64* __restrict__ gx)
{
    __shared__ __align__(16) float xs[NN];
    __shared__ __align__(16) float wlu[WLN];
    __shared__ float2 exch[2][SPAN];

    const int bid = blockIdx.x;
    const int b = bid & 31;          // same-batch stages share an XCD (bid%8 = b%8)
    const int p = bid >> 5;
    const int tid = threadIdx.x;
    const int w = tid >> 6;
    const int lane = tid & 63;

    // unified LUT: wlu[idx] = K2*sigma(G*(|m-1023|-512)), m = idx + mlo.
    // Per-block m range: m = k - 2i + 1023, k in [0,2047], i in [128p-31,128p+128]
    // -> [767-256p, 3132-256p]; out-of-range m only feeds masked/unread cells
    // (finite benign value K2). mlo odd + m0 odd -> idx even -> 8B aligned.
    const int mlo = 767 - 256 * p;
    for (int tdx = tid; tdx < NN; tdx += THREADS)
        xs[tdx] = inp[b * NN + tdx];
    for (int tdx = tid; tdx < WLN; tdx += THREADS) {
        int m = tdx + mlo;
        float val = K2;
        if ((unsigned)m <= 2046u)
            val = K2 / (1.0f + __expf(-GW * (fabsf((float)m - 1023.0f) - 512.0f)));
        wlu[tdx] = val;
    }

    const int i = 128 * p - (DD - 1) + SW * w + lane;   // owned row (may be OOB)
    const int i0 = i - lane;                            // wave's base row
    const bool rowValid = (unsigned)i < (unsigned)NN;
    int ic = min(max(i, 0), NN - 1);
    const float ti = tgt[b * NN + ic];
    const int imask = rowValid ? i : 0x3FFFFFFF;        // forces jj0 very negative
    // weight index at step d: (t<<5) + wq + d, wq = 256 + 256p - 2i (even, in [0,318])
    const int wq = 256 + 256 * p - 2 * i;

    float r1 = BIGS, r2 = BIGS;             // R(i,k-1), R(i,k-2), scaled by K2
    float dgp = (i == 0) ? 0.0f : BIGS;     // R(i-1,k-2) carry; R(-1,-1)=0
    float bndUp = BIGS;                     // lane-0 'up' feed at interval start
    float xv = 0.0f;                        // x[k - i] rotation register
    float bf1 = BIGS, bf2 = BIGS;           // producer odd-interval finals buffer
    int ackC = 0;

    __syncthreads();                        // full sync once: LDS init done

    const int fin = b * P + p;              // inbound interface (p>0)
    const int fout = fin + 1;               // outbound interface (p<P-1)
    u64* gout = gx + (size_t)fout * (RB * DD * 4);
    const u64* ginb = gx + (size_t)fin * (RB * DD * 4);

    const bool isProd = (w == NW - 1) && (p < P - 1);
    const bool isCons = (w == 0) && (p > 0);

    // consumer prefetch regs: pfa..pfd = own-row words (j=lane+1, words 0..3),
    // pba..pbd = boundary words (j=0, lane 0 only)
    u64 pfa = 0, pfb = 0, pfc = 0, pfd = 0;
    u64 pba = 0, pbb = 0, pbc = 0, pbd = 0;
    float nr1 = 0.0f, nr2 = 0.0f, nbx = 0.0f, nby = 0.0f;  // odd-half stash

    // ping-pong prefetch of the x rotation seeds for interval t=0
    int cP  = min(max(-1 - i, 0), NN - 1);
    int c0P = min(max(-i0, 0), NN - 1);
    float xpreA = xs[cP];       // -> xv init: x[kbase-1-i]
    float xpreB = xs[c0P];      // -> xf0:     x[kbase-i0]

    // loop-carried weight registers: preload interval t=0, then PIN into
    // VGPRs (asm "+v" requires the loaded value -> ds_reads complete here,
    // in-loop uses are pure VGPR reads; compiler cannot re-read from LDS)
    float wreg[DD];
    {
        const float* wp = &wlu[wq];
        #pragma unroll
        for (int h = 0; h < DD / 2; ++h) {
            float2 w2 = *reinterpret_cast<const float2*>(&wp[2 * h]);
            wreg[2 * h] = w2.x; wreg[2 * h + 1] = w2.y;
        }
        #pragma unroll
        for (int h = 0; h < DD; ++h) asm volatile("" : "+v"(wreg[h]));
        asm volatile("" : "+v"(xpreA), "+v"(xpreB));
    }

    for (int t = 0; t < NT; ++t) {
        if (t > 0) {
            // ---- producer: buffer odd finals; publish pair at even tops ----
            // r1/r2 of lanes 31..62 hold interval t-1 finals here (refresh
            // below only touches lanes 0..30).
            if (isProd) {
                if (t & 1) { bf1 = r1; bf2 = r2; }      // u0 = t-1 finals
                const bool doPub = (!(t & 1) && t >= 2) || (t == NT - 1);
                if (doPub) {
                    const int pr = ((t & 1) ? (t - 1) : (t - 2)) >> 1;
                    if (pr >= RB) {                     // slot pr&3 free?
                        while (ackC < pr + 1 - RB) {
                            __builtin_amdgcn_s_sleep(1);
                            ackC = __hip_atomic_load(&acks[fout], __ATOMIC_RELAXED,
                                                     __HIP_MEMORY_SCOPE_AGENT);
                        }
                    }
                    if (lane >= DD - 1 && lane < 63) {
                        u64* gq = gout + (size_t)(pr & (RB - 1)) * (DD * 4)
                                       + (size_t)(lane - (DD - 1)) * 4;
                        const unsigned tg = (unsigned)(pr + 1);
                        __hip_atomic_store(&gq[0], pk(bf1, tg),
                                           __ATOMIC_RELAXED, __HIP_MEMORY_SCOPE_AGENT);
                        __hip_atomic_store(&gq[1], pk(bf2, tg),
                                           __ATOMIC_RELAXED, __HIP_MEMORY_SCOPE_AGENT);
                        __hip_atomic_store(&gq[2], pk(r1, tg),
                                           __ATOMIC_RELAXED, __HIP_MEMORY_SCOPE_AGENT);
                        __hip_atomic_store(&gq[3], pk(r2, tg),
                                           __ATOMIC_RELAXED, __HIP_MEMORY_SCOPE_AGENT);
                    }
                    // ack prefetch for next gate; hides under inner loop
                    ackC = __hip_atomic_load(&acks[fout], __ATOMIC_RELAXED,
                                             __HIP_MEMORY_SCOPE_AGENT);
                }
            }
            // ---- refresh stale lanes (0..30) + boundary feed ----
            if (w > 0) {
                const int buf = (t - 1) & 1;
                if (lane < DD - 1) { float2 vv = exch[buf][SW * w + lane]; r1 = vv.x; r2 = vv.y; }
                float2 bv = exch[buf][SW * w - 1];
                float nd = dppshr(0.0f, r2);
                if (lane == 0)           { bndUp = bv.x; dgp = bv.y; }
                else if (lane <= DD - 2) dgp = nd;
            } else if (p > 0) {
                if (t & 1) {
                    // odd top: validate pair pr=(t-1)/2 (4 words), merge u0,
                    // stash u1 for the next (even) top. No sleep in the spin.
                    const int pr = (t - 1) >> 1;
                    const unsigned expect = (unsigned)(pr + 1);
                    const u64* gslot = ginb + (size_t)(pr & (RB - 1)) * (DD * 4);
                    for (;;) {
                        int ok = 1;
                        if (lane < DD - 1)
                            ok = ((unsigned)(pfa >> 32) == expect) &
                                 ((unsigned)(pfb >> 32) == expect) &
                                 ((unsigned)(pfc >> 32) == expect) &
                                 ((unsigned)(pfd >> 32) == expect);
                        if (lane == 0)
                            ok &= ((unsigned)(pba >> 32) == expect) &
                                  ((unsigned)(pbb >> 32) == expect) &
                                  ((unsigned)(pbc >> 32) == expect) &
                                  ((unsigned)(pbd >> 32) == expect);
                        if (__all(ok)) break;
                        if (lane < DD - 1) {
                            const u64* q = &gslot[(size_t)(lane + 1) * 4];
                            pfa = __hip_atomic_load(&q[0], __ATOMIC_RELAXED, __HIP_MEMORY_SCOPE_AGENT);
                            pfb = __hip_atomic_load(&q[1], __ATOMIC_RELAXED, __HIP_MEMORY_SCOPE_AGENT);
                            pfc = __hip_atomic_load(&q[2], __ATOMIC_RELAXED, __HIP_MEMORY_SCOPE_AGENT);
                            pfd = __hip_atomic_load(&q[3], __ATOMIC_RELAXED, __HIP_MEMORY_SCOPE_AGENT);
                        }
                        if (lane == 0) {
                            pba = __hip_atomic_load(&gslot[0], __ATOMIC_RELAXED, __HIP_MEMORY_SCOPE_AGENT);
                            pbb = __hip_atomic_load(&gslot[1], __ATOMIC_RELAXED, __HIP_MEMORY_SCOPE_AGENT);
                            pbc = __hip_atomic_load(&gslot[2], __ATOMIC_RELAXED, __HIP_MEMORY_SCOPE_AGENT);
                            pbd = __hip_atomic_load(&gslot[3], __ATOMIC_RELAXED, __HIP_MEMORY_SCOPE_AGENT);
                        }
                    }
                    if (lane < DD - 1) {
                        r1 = __uint_as_float((unsigned)pfa);
                        r2 = __uint_as_float((unsigned)pfb);
                        nr1 = __uint_as_float((unsigned)pfc);
                        nr2 = __uint_as_float((unsigned)pfd);
                    }
                    float nd = dppshr(0.0f, r2);
                    if (lane == 0) {
                        bndUp = __uint_as_float((unsigned)pba);
                        dgp   = __uint_as_float((unsigned)pbb);
                        nbx   = __uint_as_float((unsigned)pbc);
                        nby   = __uint_as_float((unsigned)pbd);
                    } else if (lane <= DD - 2) dgp = nd;
                    // ack value data-depends on validated tag
                    if (lane == 0)
                        __hip_atomic_store(&acks[fin], (int)(pba >> 32),
                                           __ATOMIC_RELAXED, __HIP_MEMORY_SCOPE_AGENT);
                } else {
                    // even top: pure register merge from the stashed u1 half
                    if (lane < DD - 1) { r1 = nr1; r2 = nr2; }
                    float nd = dppshr(0.0f, r2);
                    if (lane == 0)           { bndUp = nbx; dgp = nby; }
                    else if (lane <= DD - 2) dgp = nd;
                }
            } else {
                bndUp = BIGS;   // p==0, w==0: true boundary
            }
        }

        // ---- interval t compute (wreg pinned at bottom of t-1) ----
        const int kbase = t << 5;
        const int jj0 = kbase - imask;                  // j at d=0 (or very negative)

        const float xf0 = xpreB;
        xv = xpreA;
        // issue next interval's x seeds now; full interval to complete
        { int cN  = min(max(kbase + DD - 1 - i, 0), NN - 1);
          int c0N = min(max(kbase + DD - i0, 0), NN - 1);
          xpreA = xs[cN]; xpreB = xs[c0N]; }

        if (i0 >= 0 && kbase >= i0 + 63) {
            // steady: every lane has j>=0 for all d; rows >1023 compute
            // garbage that is provably never consumed
            #pragma unroll
            for (int d = 0; d < DD; ++d) STEPBODY(d, 0);
        } else {
            #pragma unroll
            for (int d = 0; d < DD; ++d) STEPBODY(d, 1);
        }
        if (t == NT - 1) break;

        // ---- bottom: wreg preload for t+1 (latency hides under publish/
        // barrier section), publish, prefetch, pin, barrier ----
        {
            const float* wp = &wlu[((t + 1) << 5) + wq];
            #pragma unroll
            for (int h = 0; h < DD / 2; ++h) {
                float2 w2 = *reinterpret_cast<const float2*>(&wp[2 * h]);
                wreg[2 * h] = w2.x; wreg[2 * h + 1] = w2.y;
            }
        }

        // intra-block publish: fresh lanes only (wave NW-1's slots are unread)
        if (w < NW - 1 && lane >= DD - 1)
            exch[t & 1][SW * w + lane] = make_float2(r1, r2);

        // consumer prefetch: pair pr=t/2 at even bottoms (validated at the
        // next odd top; producer published it ~2 periods earlier -> hit)
        if (isCons && !(t & 1)) {
            const int pr = t >> 1;
            const u64* gslot = ginb + (size_t)(pr & (RB - 1)) * (DD * 4);
            if (lane < DD - 1) {
                const u64* q = &gslot[(size_t)(lane + 1) * 4];
                pfa = __hip_atomic_load(&q[0], __ATOMIC_RELAXED, __HIP_MEMORY_SCOPE_AGENT);
                pfb = __hip_atomic_load(&q[1], __ATOMIC_RELAXED, __HIP_MEMORY_SCOPE_AGENT);
                pfc = __hip_atomic_load(&q[2], __ATOMIC_RELAXED, __HIP_MEMORY_SCOPE_AGENT);
                pfd = __hip_atomic_load(&q[3], __ATOMIC_RELAXED, __HIP_MEMORY_SCOPE_AGENT);
            }
            if (lane == 0) {
                pba = __hip_atomic_load(&gslot[0], __ATOMIC_RELAXED, __HIP_MEMORY_SCOPE_AGENT);
                pbb = __hip_atomic_load(&gslot[1], __ATOMIC_RELAXED, __HIP_MEMORY_SCOPE_AGENT);
                pbc = __hip_atomic_load(&gslot[2], __ATOMIC_RELAXED, __HIP_MEMORY_SCOPE_AGENT);
                pbd = __hip_atomic_load(&gslot[3], __ATOMIC_RELAXED, __HIP_MEMORY_SCOPE_AGENT);
            }
        }

        // pin next interval's weights + x seeds into VGPRs (waits for the
        // ds_reads HERE, before the barrier -- not inside the step chain)
        #pragma unroll
        for (int h = 0; h < DD; ++h) asm volatile("" : "+v"(wreg[h]));
        asm volatile("" : "+v"(xpreA), "+v"(xpreB));

        // LDS-only barrier: drain ds_writes, leave global ops in flight.
        asm volatile("s_waitcnt lgkmcnt(0)" ::: "memory");
        __builtin_amdgcn_s_barrier();
        asm volatile("" ::: "memory");
        __builtin_amdgcn_sched_barrier(0);
    }

    // after t=NT-1: r2 = R(i, 2046); cell (1023,1023) is at i=1023 (p=7,w=3,lane=62)
    if (i == NN - 1) partial[b] = r2 * INV_K2;
}

__global__ __launch_bounds__(64) void reduce_mean32(const float* __restrict__ partial,
                                                    float* __restrict__ out) {
    float v = (threadIdx.x < BATCH) ? partial[threadIdx.x] : 0.0f;
    #pragma unroll
    for (int off = 32; off > 0; off >>= 1) v += __shfl_down(v, off);
    if (threadIdx.x == 0) out[0] = v * (1.0f / (float)BATCH);
}

extern "C" void kernel_launch(void* const* d_in, const int* in_sizes, int n_in,
                              void* d_out, int out_size, void* d_ws, size_t ws_size,
                              hipStream_t stream) {
    const float* inp = (const float*)d_in[0];  // [B, N, 1]
    const float* tgt = (const float*)d_in[1];  // [B, N, 1]
    float* out = (float*)d_out;                // [1]

    float* partial = (float*)d_ws;                        // 32 floats
    int* acks  = (int*)((char*)d_ws + 128);               // 256 ints
    u64* gx    = (u64*)((char*)d_ws + 2048);              // 256*RB*DD*4 u64 = 1MB

    ws_init<<<513, 256, 0, stream>>>(acks, gx);
    sdtw_pipe8<<<BATCH * P, THREADS, 0, stream>>>(inp, tgt, partial, acks, gx);
    reduce_mean32<<<1, 64, 0, stream>>>(partial, out);
}

// Round 13
// 206.768 us; speedup vs baseline: 1.0122x; 1.0122x over previous
//
#include <hip/hip_runtime.h>
#include <math.h>

#define NN 1024
#define BATCH 32
#define P 8               // blocks per batch
#define NW 4              // waves per block
#define THREADS 256
#define DD 32             // diagonals per interval (needs SW >= DD-1, SW+DD <= 65)
#define SW 32             // row stride between waves
#define SPAN 160          // (NW-1)*SW + 64
#define NT 64             // ceil(2047/DD)
#define RB 4              // fabric ring slots, in PAIRS (power of 2)
#define WLN 2368          // per-block unified weight LUT length (covers m-range + guards)
#define GW 0.05f
#define K2 144.2695040888963f            // (1/gamma)*log2(e): scaled domain
#define INV_K2 0.0069314718055994531f    // gamma*ln2
#define BIGS 1.4426950408889634e11f      // 1e9 * K2

#define EXP2F(x) __builtin_amdgcn_exp2f(x)
#define LOG2F(x) __builtin_amdgcn_logf(x)   // v_log_f32 = log2

typedef unsigned long long u64;

// lanes 1..63 <- src[lane-1]; lane 0 <- oldv[0] (DPP wave_shr:1, bound_ctrl=false)
__device__ __forceinline__ float dppshr(float oldv, float src) {
    return __int_as_float(__builtin_amdgcn_update_dpp(
        __float_as_int(oldv), __float_as_int(src), 0x138, 0xF, 0xF, false));
}

// self-validating packet: {f32 value | u32 tag} in one atomic u64
__device__ __forceinline__ u64 pk(float v, unsigned tag) {
    return ((u64)tag << 32) | (u64)__float_as_uint(v);
}

// zero acks[256] + all packet words (tags must not alias across runs)
// gx = 256 interfaces * RB * DD * 4 = 131072 u64 -> 512 blocks of 256
__global__ __launch_bounds__(256) void ws_init(int* __restrict__ acks,
                                               u64* __restrict__ gx) {
    if (blockIdx.x == 512) acks[threadIdx.x] = 0;
    else gx[(size_t)blockIdx.x * 256 + threadIdx.x] = 0;
}

// Software-pipelined DP step: tail(d) consumes head-computed xvc/dkc; head(d+1)
// (xv rotation + cost — an independent dpp chain, never touching r1) is issued
// BETWEEN the exp2s and their consumption, filling the trans-latency window.
// Values computed are order-identical per cell to the original STEPBODY.
// DOMASK is compile-time 0/1; entry mask doubles as the i<0 boundary.
#define STEP2(d, DOMASK) do {                                                 \
        const float up = dppshr(((d) == 0) ? bndUp : r1, r1); /* R(i-1,k-1)*/ \
        const float dg = dgp;                                                 \
        const float left = r1;                                                \
        const float mn = fminf(fminf(dg, up), left);                          \
        const float md = __builtin_amdgcn_fmed3f(dg, up, left);               \
        const float mx = fmaxf(fmaxf(dg, up), left);                          \
        const float e1 = EXP2F(mn - md);                                      \
        const float e2 = EXP2F(mn - mx);                                      \
        float xvn = xvc, dkn = 0.0f;          /* head(d+1): independent */    \
        if ((d) < DD - 1) {                                                   \
            xvn = dppshr(xvc, xvc);           /* x[k-i] flows diagonally */   \
            const float df = ti - xvn;                                        \
            dkn = df * df * wreg[(d) + 1];    /* K2-scaled cost for d+1 */    \
        }                                                                     \
        const float ss = 1.0f + e1 + e2;                                      \
        float r = dkc + mn - LOG2F(ss);                                       \
        if (DOMASK) r = (jj0 >= -(d)) ? r : BIGS;   /* entry-side mask */     \
        r2 = r1; r1 = r; dgp = up; xvc = xvn; dkc = dkn;                      \
    } while (0)

// Overlapped-band wavefront soft-DTW, 8 CUs per batch.
// Round-17: head/tail software pipeline on the R9 (155.7us, best) skeleton.
// Accounting: per-step wall 184 cy = issue ~85 + chain ~95 with ~zero overlap
// -- in-order issue + per-step program ordering stalls the wave on exp2/log2
// dependents while step d+1's independent work (xv dpp chain, diff, dk) sits
// below. STEP2 hoists that work into the trans-latency window via one-step
// rotation registers (xvc/dkc). Cell values order-identical; protocol, fabric
// pairing, geometry byte-identical to R9. R12's pins/min3 reverted (regressed).
__global__ __launch_bounds__(THREADS) void sdtw_pipe8(
        const float* __restrict__ inp, const float* __restrict__ tgt,
        float* __restrict__ partial, int* __restrict__ acks,
        u64* __restrict__ gx)
{
    __shared__ __align__(16) float xs[NN];
    __shared__ __align__(16) float wlu[WLN];
    __shared__ float2 exch[2][SPAN];

    const int bid = blockIdx.x;
    const int b = bid & 31;          // same-batch stages share an XCD (bid%8 = b%8)
    const int p = bid >> 5;
    const int tid = threadIdx.x;
    const int w = tid >> 6;
    const int lane = tid & 63;

    // unified LUT: wlu[idx] = K2*sigma(G*(|m-1023|-512)), m = idx + mlo.
    // Per-block m range: m = k - 2i + 1023, k in [0,2047], i in [128p-31,128p+128]
    // -> [767-256p, 3132-256p]; out-of-range m only feeds masked/unread cells
    // (finite benign value K2). mlo odd + m0 odd -> idx even -> 8B aligned.
    const int mlo = 767 - 256 * p;
    for (int tdx = tid; tdx < NN; tdx += THREADS)
        xs[tdx] = inp[b * NN + tdx];
    for (int tdx = tid; tdx < WLN; tdx += THREADS) {
        int m = tdx + mlo;
        float val = K2;
        if ((unsigned)m <= 2046u)
            val = K2 / (1.0f + __expf(-GW * (fabsf((float)m - 1023.0f) - 512.0f)));
        wlu[tdx] = val;
    }

    const int i = 128 * p - (DD - 1) + SW * w + lane;   // owned row (may be OOB)
    const int i0 = i - lane;                            // wave's base row
    const bool rowValid = (unsigned)i < (unsigned)NN;
    int ic = min(max(i, 0), NN - 1);
    const float ti = tgt[b * NN + ic];
    const int imask = rowValid ? i : 0x3FFFFFFF;        // forces jj0 very negative
    // weight index at step d: (t<<5) + wq + d, wq = 256 + 256p - 2i (even, in [0,318])
    const int wq = 256 + 256 * p - 2 * i;

    float r1 = BIGS, r2 = BIGS;             // R(i,k-1), R(i,k-2), scaled by K2
    float dgp = (i == 0) ? 0.0f : BIGS;     // R(i-1,k-2) carry; R(-1,-1)=0
    float bndUp = BIGS;                     // lane-0 'up' feed at interval start
    float bf1 = BIGS, bf2 = BIGS;           // producer odd-interval finals buffer
    int ackC = 0;

    __syncthreads();                        // full sync once: LDS init done

    const int fin = b * P + p;              // inbound interface (p>0)
    const int fout = fin + 1;               // outbound interface (p<P-1)
    u64* gout = gx + (size_t)fout * (RB * DD * 4);
    const u64* ginb = gx + (size_t)fin * (RB * DD * 4);

    const bool isProd = (w == NW - 1) && (p < P - 1);
    const bool isCons = (w == 0) && (p > 0);

    // consumer prefetch regs: pfa..pfd = own-row words (j=lane+1, words 0..3),
    // pba..pbd = boundary words (j=0, lane 0 only)
    u64 pfa = 0, pfb = 0, pfc = 0, pfd = 0;
    u64 pba = 0, pbb = 0, pbc = 0, pbd = 0;
    float nr1 = 0.0f, nr2 = 0.0f, nbx = 0.0f, nby = 0.0f;  // odd-half stash

    // ping-pong prefetch of the x rotation seeds for interval t=0
    int cP  = min(max(-1 - i, 0), NN - 1);
    int c0P = min(max(-i0, 0), NN - 1);
    float xpreA = xs[cP];       // -> xv init: x[kbase-1-i]
    float xpreB = xs[c0P];      // -> xf0:     x[kbase-i0]

    for (int t = 0; t < NT; ++t) {
        if (t > 0) {
            // ---- producer: buffer odd finals; publish pair at even tops ----
            // r1/r2 of lanes 31..62 hold interval t-1 finals here (refresh
            // below only touches lanes 0..30).
            if (isProd) {
                if (t & 1) { bf1 = r1; bf2 = r2; }      // u0 = t-1 finals
                const bool doPub = (!(t & 1) && t >= 2) || (t == NT - 1);
                if (doPub) {
                    const int pr = ((t & 1) ? (t - 1) : (t - 2)) >> 1;
                    if (pr >= RB) {                     // slot pr&3 free?
                        while (ackC < pr + 1 - RB) {
                            __builtin_amdgcn_s_sleep(1);
                            ackC = __hip_atomic_load(&acks[fout], __ATOMIC_RELAXED,
                                                     __HIP_MEMORY_SCOPE_AGENT);
                        }
                    }
                    if (lane >= DD - 1 && lane < 63) {
                        u64* gq = gout + (size_t)(pr & (RB - 1)) * (DD * 4)
                                       + (size_t)(lane - (DD - 1)) * 4;
                        const unsigned tg = (unsigned)(pr + 1);
                        __hip_atomic_store(&gq[0], pk(bf1, tg),
                                           __ATOMIC_RELAXED, __HIP_MEMORY_SCOPE_AGENT);
                        __hip_atomic_store(&gq[1], pk(bf2, tg),
                                           __ATOMIC_RELAXED, __HIP_MEMORY_SCOPE_AGENT);
                        __hip_atomic_store(&gq[2], pk(r1, tg),
                                           __ATOMIC_RELAXED, __HIP_MEMORY_SCOPE_AGENT);
                        __hip_atomic_store(&gq[3], pk(r2, tg),
                                           __ATOMIC_RELAXED, __HIP_MEMORY_SCOPE_AGENT);
                    }
                    // ack prefetch for next gate; hides under inner loop
                    ackC = __hip_atomic_load(&acks[fout], __ATOMIC_RELAXED,
                                             __HIP_MEMORY_SCOPE_AGENT);
                }
            }
            // ---- refresh stale lanes (0..30) + boundary feed ----
            if (w > 0) {
                const int buf = (t - 1) & 1;
                if (lane < DD - 1) { float2 vv = exch[buf][SW * w + lane]; r1 = vv.x; r2 = vv.y; }
                float2 bv = exch[buf][SW * w - 1];
                float nd = dppshr(0.0f, r2);
                if (lane == 0)           { bndUp = bv.x; dgp = bv.y; }
                else if (lane <= DD - 2) dgp = nd;
            } else if (p > 0) {
                if (t & 1) {
                    // odd top: validate pair pr=(t-1)/2 (4 words), merge u0,
                    // stash u1 for the next (even) top. No sleep in the spin.
                    const int pr = (t - 1) >> 1;
                    const unsigned expect = (unsigned)(pr + 1);
                    const u64* gslot = ginb + (size_t)(pr & (RB - 1)) * (DD * 4);
                    for (;;) {
                        int ok = 1;
                        if (lane < DD - 1)
                            ok = ((unsigned)(pfa >> 32) == expect) &
                                 ((unsigned)(pfb >> 32) == expect) &
                                 ((unsigned)(pfc >> 32) == expect) &
                                 ((unsigned)(pfd >> 32) == expect);
                        if (lane == 0)
                            ok &= ((unsigned)(pba >> 32) == expect) &
                                  ((unsigned)(pbb >> 32) == expect) &
                                  ((unsigned)(pbc >> 32) == expect) &
                                  ((unsigned)(pbd >> 32) == expect);
                        if (__all(ok)) break;
                        if (lane < DD - 1) {
                            const u64* q = &gslot[(size_t)(lane + 1) * 4];
                            pfa = __hip_atomic_load(&q[0], __ATOMIC_RELAXED, __HIP_MEMORY_SCOPE_AGENT);
                            pfb = __hip_atomic_load(&q[1], __ATOMIC_RELAXED, __HIP_MEMORY_SCOPE_AGENT);
                            pfc = __hip_atomic_load(&q[2], __ATOMIC_RELAXED, __HIP_MEMORY_SCOPE_AGENT);
                            pfd = __hip_atomic_load(&q[3], __ATOMIC_RELAXED, __HIP_MEMORY_SCOPE_AGENT);
                        }
                        if (lane == 0) {
                            pba = __hip_atomic_load(&gslot[0], __ATOMIC_RELAXED, __HIP_MEMORY_SCOPE_AGENT);
                            pbb = __hip_atomic_load(&gslot[1], __ATOMIC_RELAXED, __HIP_MEMORY_SCOPE_AGENT);
                            pbc = __hip_atomic_load(&gslot[2], __ATOMIC_RELAXED, __HIP_MEMORY_SCOPE_AGENT);
                            pbd = __hip_atomic_load(&gslot[3], __ATOMIC_RELAXED, __HIP_MEMORY_SCOPE_AGENT);
                        }
                    }
                    if (lane < DD - 1) {
                        r1 = __uint_as_float((unsigned)pfa);
                        r2 = __uint_as_float((unsigned)pfb);
                        nr1 = __uint_as_float((unsigned)pfc);
                        nr2 = __uint_as_float((unsigned)pfd);
                    }
                    float nd = dppshr(0.0f, r2);
                    if (lane == 0) {
                        bndUp = __uint_as_float((unsigned)pba);
                        dgp   = __uint_as_float((unsigned)pbb);
                        nbx   = __uint_as_float((unsigned)pbc);
                        nby   = __uint_as_float((unsigned)pbd);
                    } else if (lane <= DD - 2) dgp = nd;
                    // ack value data-depends on validated tag
                    if (lane == 0)
                        __hip_atomic_store(&acks[fin], (int)(pba >> 32),
                                           __ATOMIC_RELAXED, __HIP_MEMORY_SCOPE_AGENT);
                } else {
                    // even top: pure register merge from the stashed u1 half
                    if (lane < DD - 1) { r1 = nr1; r2 = nr2; }
                    float nd = dppshr(0.0f, r2);
                    if (lane == 0)           { bndUp = nbx; dgp = nby; }
                    else if (lane <= DD - 2) dgp = nd;
                }
            } else {
                bndUp = BIGS;   // p==0, w==0: true boundary
            }
        }

        // ---- interval t compute ----
        const int kbase = t << 5;
        const int jj0 = kbase - imask;                  // j at d=0 (or very negative)

        // preload this interval's 32 consecutive weights into registers
        const float* wp = &wlu[kbase + wq];
        float wreg[DD];
        #pragma unroll
        for (int h = 0; h < DD / 2; ++h) {
            float2 w2 = *reinterpret_cast<const float2*>(&wp[2 * h]);
            wreg[2 * h] = w2.x; wreg[2 * h + 1] = w2.y;
        }

        // head(0): xv for step 0 + its cost (identical values to original)
        const float xf0 = xpreB;
        float xvc = dppshr(xf0, xpreA);
        float dkc;
        { const float df0 = ti - xvc; dkc = df0 * df0 * wreg[0]; }

        // issue next interval's x seeds now; full interval to complete
        { int cN  = min(max(kbase + DD - 1 - i, 0), NN - 1);
          int c0N = min(max(kbase + DD - i0, 0), NN - 1);
          xpreA = xs[cN]; xpreB = xs[c0N]; }

        if (i0 >= 0 && kbase >= i0 + 63) {
            // steady: every lane has j>=0 for all d; rows >1023 compute
            // garbage that is provably never consumed
            #pragma unroll
            for (int d = 0; d < DD; ++d) STEP2(d, 0);
        } else {
            #pragma unroll
            for (int d = 0; d < DD; ++d) STEP2(d, 1);
        }
        if (t == NT - 1) break;

        // intra-block publish: fresh lanes only (wave NW-1's slots are unread)
        if (w < NW - 1 && lane >= DD - 1)
            exch[t & 1][SW * w + lane] = make_float2(r1, r2);

        // consumer prefetch: pair pr=t/2 at even bottoms (validated at the
        // next odd top; producer published it ~2 periods earlier -> hit)
        if (isCons && !(t & 1)) {
            const int pr = t >> 1;
            const u64* gslot = ginb + (size_t)(pr & (RB - 1)) * (DD * 4);
            if (lane < DD - 1) {
                const u64* q = &gslot[(size_t)(lane + 1) * 4];
                pfa = __hip_atomic_load(&q[0], __ATOMIC_RELAXED, __HIP_MEMORY_SCOPE_AGENT);
                pfb = __hip_atomic_load(&q[1], __ATOMIC_RELAXED, __HIP_MEMORY_SCOPE_AGENT);
                pfc = __hip_atomic_load(&q[2], __ATOMIC_RELAXED, __HIP_MEMORY_SCOPE_AGENT);
                pfd = __hip_atomic_load(&q[3], __ATOMIC_RELAXED, __HIP_MEMORY_SCOPE_AGENT);
            }
            if (lane == 0) {
                pba = __hip_atomic_load(&gslot[0], __ATOMIC_RELAXED, __HIP_MEMORY_SCOPE_AGENT);
                pbb = __hip_atomic_load(&gslot[1], __ATOMIC_RELAXED, __HIP_MEMORY_SCOPE_AGENT);
                pbc = __hip_atomic_load(&gslot[2], __ATOMIC_RELAXED, __HIP_MEMORY_SCOPE_AGENT);
                pbd = __hip_atomic_load(&gslot[3], __ATOMIC_RELAXED, __HIP_MEMORY_SCOPE_AGENT);
            }
        }

        // LDS-only barrier: drain ds_writes, leave global ops in flight.
        asm volatile("s_waitcnt lgkmcnt(0)" ::: "memory");
        __builtin_amdgcn_s_barrier();
        asm volatile("" ::: "memory");
        __builtin_amdgcn_sched_barrier(0);
    }

    // after t=NT-1: r2 = R(i, 2046); cell (1023,1023) is at i=1023 (p=7,w=3,lane=62)
    if (i == NN - 1) partial[b] = r2 * INV_K2;
}

__global__ __launch_bounds__(64) void reduce_mean32(const float* __restrict__ partial,
                                                    float* __restrict__ out) {
    float v = (threadIdx.x < BATCH) ? partial[threadIdx.x] : 0.0f;
    #pragma unroll
    for (int off = 32; off > 0; off >>= 1) v += __shfl_down(v, off);
    if (threadIdx.x == 0) out[0] = v * (1.0f / (float)BATCH);
}

extern "C" void kernel_launch(void* const* d_in, const int* in_sizes, int n_in,
                              void* d_out, int out_size, void* d_ws, size_t ws_size,
                              hipStream_t stream) {
    const float* inp = (const float*)d_in[0];  // [B, N, 1]
    const float* tgt = (const float*)d_in[1];  // [B, N, 1]
    float* out = (float*)d_out;                // [1]

    float* partial = (float*)d_ws;                        // 32 floats
    int* acks  = (int*)((char*)d_ws + 128);               // 256 ints
    u64* gx    = (u64*)((char*)d_ws + 2048);              // 256*RB*DD*4 u64 = 1MB

    ws_init<<<513, 256, 0, stream>>>(acks, gx);
    sdtw_pipe8<<<BATCH * P, THREADS, 0, stream>>>(inp, tgt, partial, acks, gx);
    reduce_mean32<<<1, 64, 0, stream>>>(partial, out);
}

// Round 14
// 205.673 us; speedup vs baseline: 1.0175x; 1.0053x over previous
//
#include <hip/hip_runtime.h>
#include <math.h>

#define NN 1024
#define BATCH 32
#define P 8               // blocks per batch
#define NW 4              // waves per block
#define THREADS 256
#define DD 32             // diagonals per interval (needs SW >= DD-1, SW+DD <= 65)
#define SW 32             // row stride between waves
#define SPAN 160          // (NW-1)*SW + 64
#define NT 64             // ceil(2047/DD)
#define RB 4              // fabric ring slots, in PAIRS (power of 2)
#define WLN 2368          // per-block unified weight LUT length (covers m-range + guards)
#define GW 0.05f
#define K2 144.2695040888963f            // (1/gamma)*log2(e): scaled domain
#define INV_K2 0.0069314718055994531f    // gamma*ln2
#define BIGS 1.4426950408889634e11f      // 1e9 * K2

#define EXP2F(x) __builtin_amdgcn_exp2f(x)
#define LOG2F(x) __builtin_amdgcn_logf(x)   // v_log_f32 = log2

typedef unsigned long long u64;

// lanes 1..63 <- src[lane-1]; lane 0 <- oldv[0] (DPP wave_shr:1, bound_ctrl=false)
__device__ __forceinline__ float dppshr(float oldv, float src) {
    return __int_as_float(__builtin_amdgcn_update_dpp(
        __float_as_int(oldv), __float_as_int(src), 0x138, 0xF, 0xF, false));
}

// self-validating packet: {f32 value | u32 tag} in one atomic u64
__device__ __forceinline__ u64 pk(float v, unsigned tag) {
    return ((u64)tag << 32) | (u64)__float_as_uint(v);
}

// zero acks[256] + all packet words (tags must not alias across runs)
// gx = 256 interfaces * RB * DD * 4 = 131072 u64 -> 512 blocks of 256
__global__ __launch_bounds__(256) void ws_init(int* __restrict__ acks,
                                               u64* __restrict__ gx) {
    if (blockIdx.x == 512) acks[threadIdx.x] = 0;
    else gx[(size_t)blockIdx.x * 256 + threadIdx.x] = 0;
}

// One DP step. DOMASK is compile-time 0/1; entry mask doubles as the i<0
// boundary (R(-1,j)=inf), so the wave containing rows i<0 keeps it forever.
#define STEPBODY(d, DOMASK) do {                                              \
        xv = dppshr(((d) == 0) ? xf0 : xv, xv);     /* x[k-i] flows diag */   \
        const float up = dppshr(((d) == 0) ? bndUp : r1, r1); /* R(i-1,k-1)*/ \
        const float dg = dgp;                                                 \
        const float left = r1;                                                \
        const float diff = ti - xv;                                           \
        const float dk = diff * diff * wreg[(d)];   /* K2-scaled cost */      \
        const float mn = fminf(fminf(dg, up), left);                          \
        const float md = __builtin_amdgcn_fmed3f(dg, up, left);               \
        const float mx = fmaxf(fmaxf(dg, up), left);                          \
        const float ss = 1.0f + EXP2F(mn - md) + EXP2F(mn - mx);              \
        float r = dk + mn - LOG2F(ss);                                        \
        if (DOMASK) r = (jj0 >= -(d)) ? r : BIGS;   /* entry-side mask */     \
        r2 = r1; r1 = r; dgp = up;                                            \
    } while (0)

// Overlapped-band wavefront soft-DTW, 8 CUs per batch.
// Round-18 (FINAL): revert to the R9 configuration -- the best verified
// variant (155.7us kernel / 204.7us total, absmax 0). Thirteen structures
// bracket the design space: sync mechanism (R1/R5/R8), ring depth & event
// count (R6/R9), publish timing (R8), band vs fixed-row (R7), DD in
// {16,32,48} (R4/R10), waves/SIMD in {1,2} (R2/R4/R10), register budget &
// pinning (R11/R12), instruction selection (R12), SW-pipelining (R13).
// Accounting closure: wall = 2048 steps x 184 cy; issue ~85 cy/step (VALU
// 46%), dependent chain ~70-95 cy, and the residual is not fillable in-wave
// (R13 null) nor cross-wave at profit (R10: 2 waves/SIMD -> issue-port
// saturation, wall 214). This kernel sits at the constrained optimum of the
// family: DD=32/NW=4/1 wave-per-SIMD, paired fabric handoff (2-interval
// packets, natural lag-2, fabric events halved), LDS-only barrier.
__global__ __launch_bounds__(THREADS) void sdtw_pipe8(
        const float* __restrict__ inp, const float* __restrict__ tgt,
        float* __restrict__ partial, int* __restrict__ acks,
        u64* __restrict__ gx)
{
    __shared__ __align__(16) float xs[NN];
    __shared__ __align__(16) float wlu[WLN];
    __shared__ float2 exch[2][SPAN];

    const int bid = blockIdx.x;
    const int b = bid & 31;          // same-batch stages share an XCD (bid%8 = b%8)
    const int p = bid >> 5;
    const int tid = threadIdx.x;
    const int w = tid >> 6;
    const int lane = tid & 63;

    // unified LUT: wlu[idx] = K2*sigma(G*(|m-1023|-512)), m = idx + mlo.
    // Per-block m range: m = k - 2i + 1023, k in [0,2047], i in [128p-31,128p+128]
    // -> [767-256p, 3132-256p]; out-of-range m only feeds masked/unread cells
    // (finite benign value K2). mlo odd + m0 odd -> idx even -> 8B aligned.
    const int mlo = 767 - 256 * p;
    for (int tdx = tid; tdx < NN; tdx += THREADS)
        xs[tdx] = inp[b * NN + tdx];
    for (int tdx = tid; tdx < WLN; tdx += THREADS) {
        int m = tdx + mlo;
        float val = K2;
        if ((unsigned)m <= 2046u)
            val = K2 / (1.0f + __expf(-GW * (fabsf((float)m - 1023.0f) - 512.0f)));
        wlu[tdx] = val;
    }

    const int i = 128 * p - (DD - 1) + SW * w + lane;   // owned row (may be OOB)
    const int i0 = i - lane;                            // wave's base row
    const bool rowValid = (unsigned)i < (unsigned)NN;
    int ic = min(max(i, 0), NN - 1);
    const float ti = tgt[b * NN + ic];
    const int imask = rowValid ? i : 0x3FFFFFFF;        // forces jj0 very negative
    // weight index at step d: (t<<5) + wq + d, wq = 256 + 256p - 2i (even, in [0,318])
    const int wq = 256 + 256 * p - 2 * i;

    float r1 = BIGS, r2 = BIGS;             // R(i,k-1), R(i,k-2), scaled by K2
    float dgp = (i == 0) ? 0.0f : BIGS;     // R(i-1,k-2) carry; R(-1,-1)=0
    float bndUp = BIGS;                     // lane-0 'up' feed at interval start
    float xv = 0.0f;                        // x[k - i] rotation register
    float bf1 = BIGS, bf2 = BIGS;           // producer odd-interval finals buffer
    int ackC = 0;

    __syncthreads();                        // full sync once: LDS init done

    const int fin = b * P + p;              // inbound interface (p>0)
    const int fout = fin + 1;               // outbound interface (p<P-1)
    u64* gout = gx + (size_t)fout * (RB * DD * 4);
    const u64* ginb = gx + (size_t)fin * (RB * DD * 4);

    const bool isProd = (w == NW - 1) && (p < P - 1);
    const bool isCons = (w == 0) && (p > 0);

    // consumer prefetch regs: pfa..pfd = own-row words (j=lane+1, words 0..3),
    // pba..pbd = boundary words (j=0, lane 0 only)
    u64 pfa = 0, pfb = 0, pfc = 0, pfd = 0;
    u64 pba = 0, pbb = 0, pbc = 0, pbd = 0;
    float nr1 = 0.0f, nr2 = 0.0f, nbx = 0.0f, nby = 0.0f;  // odd-half stash

    // ping-pong prefetch of the x rotation seeds for interval t=0
    int cP  = min(max(-1 - i, 0), NN - 1);
    int c0P = min(max(-i0, 0), NN - 1);
    float xpreA = xs[cP];       // -> xv init: x[kbase-1-i]
    float xpreB = xs[c0P];      // -> xf0:     x[kbase-i0]

    for (int t = 0; t < NT; ++t) {
        if (t > 0) {
            // ---- producer: buffer odd finals; publish pair at even tops ----
            // r1/r2 of lanes 31..62 hold interval t-1 finals here (refresh
            // below only touches lanes 0..30).
            if (isProd) {
                if (t & 1) { bf1 = r1; bf2 = r2; }      // u0 = t-1 finals
                const bool doPub = (!(t & 1) && t >= 2) || (t == NT - 1);
                if (doPub) {
                    const int pr = ((t & 1) ? (t - 1) : (t - 2)) >> 1;
                    if (pr >= RB) {                     // slot pr&3 free?
                        while (ackC < pr + 1 - RB) {
                            __builtin_amdgcn_s_sleep(1);
                            ackC = __hip_atomic_load(&acks[fout], __ATOMIC_RELAXED,
                                                     __HIP_MEMORY_SCOPE_AGENT);
                        }
                    }
                    if (lane >= DD - 1 && lane < 63) {
                        u64* gq = gout + (size_t)(pr & (RB - 1)) * (DD * 4)
                                       + (size_t)(lane - (DD - 1)) * 4;
                        const unsigned tg = (unsigned)(pr + 1);
                        __hip_atomic_store(&gq[0], pk(bf1, tg),
                                           __ATOMIC_RELAXED, __HIP_MEMORY_SCOPE_AGENT);
                        __hip_atomic_store(&gq[1], pk(bf2, tg),
                                           __ATOMIC_RELAXED, __HIP_MEMORY_SCOPE_AGENT);
                        __hip_atomic_store(&gq[2], pk(r1, tg),
                                           __ATOMIC_RELAXED, __HIP_MEMORY_SCOPE_AGENT);
                        __hip_atomic_store(&gq[3], pk(r2, tg),
                                           __ATOMIC_RELAXED, __HIP_MEMORY_SCOPE_AGENT);
                    }
                    // ack prefetch for next gate; hides under inner loop
                    ackC = __hip_atomic_load(&acks[fout], __ATOMIC_RELAXED,
                                             __HIP_MEMORY_SCOPE_AGENT);
                }
            }
            // ---- refresh stale lanes (0..30) + boundary feed ----
            if (w > 0) {
                const int buf = (t - 1) & 1;
                if (lane < DD - 1) { float2 vv = exch[buf][SW * w + lane]; r1 = vv.x; r2 = vv.y; }
                float2 bv = exch[buf][SW * w - 1];
                float nd = dppshr(0.0f, r2);
                if (lane == 0)           { bndUp = bv.x; dgp = bv.y; }
                else if (lane <= DD - 2) dgp = nd;
            } else if (p > 0) {
                if (t & 1) {
                    // odd top: validate pair pr=(t-1)/2 (4 words), merge u0,
                    // stash u1 for the next (even) top. No sleep in the spin.
                    const int pr = (t - 1) >> 1;
                    const unsigned expect = (unsigned)(pr + 1);
                    const u64* gslot = ginb + (size_t)(pr & (RB - 1)) * (DD * 4);
                    for (;;) {
                        int ok = 1;
                        if (lane < DD - 1)
                            ok = ((unsigned)(pfa >> 32) == expect) &
                                 ((unsigned)(pfb >> 32) == expect) &
                                 ((unsigned)(pfc >> 32) == expect) &
                                 ((unsigned)(pfd >> 32) == expect);
                        if (lane == 0)
                            ok &= ((unsigned)(pba >> 32) == expect) &
                                  ((unsigned)(pbb >> 32) == expect) &
                                  ((unsigned)(pbc >> 32) == expect) &
                                  ((unsigned)(pbd >> 32) == expect);
                        if (__all(ok)) break;
                        if (lane < DD - 1) {
                            const u64* q = &gslot[(size_t)(lane + 1) * 4];
                            pfa = __hip_atomic_load(&q[0], __ATOMIC_RELAXED, __HIP_MEMORY_SCOPE_AGENT);
                            pfb = __hip_atomic_load(&q[1], __ATOMIC_RELAXED, __HIP_MEMORY_SCOPE_AGENT);
                            pfc = __hip_atomic_load(&q[2], __ATOMIC_RELAXED, __HIP_MEMORY_SCOPE_AGENT);
                            pfd = __hip_atomic_load(&q[3], __ATOMIC_RELAXED, __HIP_MEMORY_SCOPE_AGENT);
                        }
                        if (lane == 0) {
                            pba = __hip_atomic_load(&gslot[0], __ATOMIC_RELAXED, __HIP_MEMORY_SCOPE_AGENT);
                            pbb = __hip_atomic_load(&gslot[1], __ATOMIC_RELAXED, __HIP_MEMORY_SCOPE_AGENT);
                            pbc = __hip_atomic_load(&gslot[2], __ATOMIC_RELAXED, __HIP_MEMORY_SCOPE_AGENT);
                            pbd = __hip_atomic_load(&gslot[3], __ATOMIC_RELAXED, __HIP_MEMORY_SCOPE_AGENT);
                        }
                    }
                    if (lane < DD - 1) {
                        r1 = __uint_as_float((unsigned)pfa);
                        r2 = __uint_as_float((unsigned)pfb);
                        nr1 = __uint_as_float((unsigned)pfc);
                        nr2 = __uint_as_float((unsigned)pfd);
                    }
                    float nd = dppshr(0.0f, r2);
                    if (lane == 0) {
                        bndUp = __uint_as_float((unsigned)pba);
                        dgp   = __uint_as_float((unsigned)pbb);
                        nbx   = __uint_as_float((unsigned)pbc);
                        nby   = __uint_as_float((unsigned)pbd);
                    } else if (lane <= DD - 2) dgp = nd;
                    // ack value data-depends on validated tag
                    if (lane == 0)
                        __hip_atomic_store(&acks[fin], (int)(pba >> 32),
                                           __ATOMIC_RELAXED, __HIP_MEMORY_SCOPE_AGENT);
                } else {
                    // even top: pure register merge from the stashed u1 half
                    if (lane < DD - 1) { r1 = nr1; r2 = nr2; }
                    float nd = dppshr(0.0f, r2);
                    if (lane == 0)           { bndUp = nbx; dgp = nby; }
                    else if (lane <= DD - 2) dgp = nd;
                }
            } else {
                bndUp = BIGS;   // p==0, w==0: true boundary
            }
        }

        // ---- interval t compute ----
        const int kbase = t << 5;
        const int jj0 = kbase - imask;                  // j at d=0 (or very negative)

        // preload this interval's 32 consecutive weights into registers
        const float* wp = &wlu[kbase + wq];
        float wreg[DD];
        #pragma unroll
        for (int h = 0; h < DD / 2; ++h) {
            float2 w2 = *reinterpret_cast<const float2*>(&wp[2 * h]);
            wreg[2 * h] = w2.x; wreg[2 * h + 1] = w2.y;
        }

        const float xf0 = xpreB;
        xv = xpreA;
        // issue next interval's x seeds now; full interval to complete
        { int cN  = min(max(kbase + DD - 1 - i, 0), NN - 1);
          int c0N = min(max(kbase + DD - i0, 0), NN - 1);
          xpreA = xs[cN]; xpreB = xs[c0N]; }

        if (i0 >= 0 && kbase >= i0 + 63) {
            // steady: every lane has j>=0 for all d; rows >1023 compute
            // garbage that is provably never consumed
            #pragma unroll
            for (int d = 0; d < DD; ++d) STEPBODY(d, 0);
        } else {
            #pragma unroll
            for (int d = 0; d < DD; ++d) STEPBODY(d, 1);
        }
        if (t == NT - 1) break;

        // intra-block publish: fresh lanes only (wave NW-1's slots are unread)
        if (w < NW - 1 && lane >= DD - 1)
            exch[t & 1][SW * w + lane] = make_float2(r1, r2);

        // consumer prefetch: pair pr=t/2 at even bottoms (validated at the
        // next odd top; producer published it ~2 periods earlier -> hit)
        if (isCons && !(t & 1)) {
            const int pr = t >> 1;
            const u64* gslot = ginb + (size_t)(pr & (RB - 1)) * (DD * 4);
            if (lane < DD - 1) {
                const u64* q = &gslot[(size_t)(lane + 1) * 4];
                pfa = __hip_atomic_load(&q[0], __ATOMIC_RELAXED, __HIP_MEMORY_SCOPE_AGENT);
                pfb = __hip_atomic_load(&q[1], __ATOMIC_RELAXED, __HIP_MEMORY_SCOPE_AGENT);
                pfc = __hip_atomic_load(&q[2], __ATOMIC_RELAXED, __HIP_MEMORY_SCOPE_AGENT);
                pfd = __hip_atomic_load(&q[3], __ATOMIC_RELAXED, __HIP_MEMORY_SCOPE_AGENT);
            }
            if (lane == 0) {
                pba = __hip_atomic_load(&gslot[0], __ATOMIC_RELAXED, __HIP_MEMORY_SCOPE_AGENT);
                pbb = __hip_atomic_load(&gslot[1], __ATOMIC_RELAXED, __HIP_MEMORY_SCOPE_AGENT);
                pbc = __hip_atomic_load(&gslot[2], __ATOMIC_RELAXED, __HIP_MEMORY_SCOPE_AGENT);
                pbd = __hip_atomic_load(&gslot[3], __ATOMIC_RELAXED, __HIP_MEMORY_SCOPE_AGENT);
            }
        }

        // LDS-only barrier: drain ds_writes, leave global ops in flight.
        asm volatile("s_waitcnt lgkmcnt(0)" ::: "memory");
        __builtin_amdgcn_s_barrier();
        asm volatile("" ::: "memory");
        __builtin_amdgcn_sched_barrier(0);
    }

    // after t=NT-1: r2 = R(i, 2046); cell (1023,1023) is at i=1023 (p=7,w=3,lane=62)
    if (i == NN - 1) partial[b] = r2 * INV_K2;
}

__global__ __launch_bounds__(64) void reduce_mean32(const float* __restrict__ partial,
                                                    float* __restrict__ out) {
    float v = (threadIdx.x < BATCH) ? partial[threadIdx.x] : 0.0f;
    #pragma unroll
    for (int off = 32; off > 0; off >>= 1) v += __shfl_down(v, off);
    if (threadIdx.x == 0) out[0] = v * (1.0f / (float)BATCH);
}

extern "C" void kernel_launch(void* const* d_in, const int* in_sizes, int n_in,
                              void* d_out, int out_size, void* d_ws, size_t ws_size,
                              hipStream_t stream) {
    const float* inp = (const float*)d_in[0];  // [B, N, 1]
    const float* tgt = (const float*)d_in[1];  // [B, N, 1]
    float* out = (float*)d_out;                // [1]

    float* partial = (float*)d_ws;                        // 32 floats
    int* acks  = (int*)((char*)d_ws + 128);               // 256 ints
    u64* gx    = (u64*)((char*)d_ws + 2048);              // 256*RB*DD*4 u64 = 1MB

    ws_init<<<513, 256, 0, stream>>>(acks, gx);
    sdtw_pipe8<<<BATCH * P, THREADS, 0, stream>>>(inp, tgt, partial, acks, gx);
    reduce_mean32<<<1, 64, 0, stream>>>(partial, out);
}